// Round 5
// baseline (373.627 us; speedup 1.0000x reference)
//
#include <hip/hip_runtime.h>
#include <cstdint>

typedef _Float16 f16;
typedef __attribute__((ext_vector_type(2))) _Float16 f16x2;
typedef __attribute__((ext_vector_type(4))) _Float16 f16x4;
typedef __attribute__((ext_vector_type(8))) _Float16 f16x8;
typedef __attribute__((ext_vector_type(4))) float f32x4;

#if defined(__has_builtin)
# if __has_builtin(__builtin_amdgcn_fdot2)
#  define HAVE_FDOT2 1
# endif
#endif

// ---------------- CSR build ----------------

__global__ void hist_kernel(const int* __restrict__ dst, int* __restrict__ cnt, int E) {
    int e = blockIdx.x * blockDim.x + threadIdx.x;
    if (e < E) atomicAdd(&cnt[dst[e]], 1);
}

__global__ __launch_bounds__(256) void block_scan_kernel(
    const int* __restrict__ cnt, int* __restrict__ rowptr,
    int* __restrict__ partials, int n) {
    __shared__ int lds[256];
    int tid = threadIdx.x;
    int i = blockIdx.x * 256 + tid;
    int v = (i < n) ? cnt[i] : 0;
    lds[tid] = v;
    __syncthreads();
    for (int off = 1; off < 256; off <<= 1) {
        int t = (tid >= off) ? lds[tid - off] : 0;
        __syncthreads();
        lds[tid] += t;
        __syncthreads();
    }
    if (i < n) rowptr[i + 1] = lds[tid];
    if (tid == 255) partials[blockIdx.x] = lds[255];
}

__global__ __launch_bounds__(256) void partial_scan_kernel(int* __restrict__ partials, int nb) {
    __shared__ int lds[256];
    int tid = threadIdx.x;
    int v = (tid < nb) ? partials[tid] : 0;
    lds[tid] = v;
    __syncthreads();
    for (int off = 1; off < 256; off <<= 1) {
        int t = (tid >= off) ? lds[tid - off] : 0;
        __syncthreads();
        lds[tid] += t;
        __syncthreads();
    }
    if (tid < nb) partials[tid] = lds[tid] - v;  // exclusive
}

__global__ __launch_bounds__(256) void add_offsets_kernel(
    int* __restrict__ rowptr, const int* __restrict__ partials, int n) {
    int i = blockIdx.x * 256 + threadIdx.x;
    if (i < n) rowptr[i + 1] += partials[blockIdx.x];
    if (i == 0) rowptr[0] = 0;
}

__global__ void scatter_kernel(const int* __restrict__ src, const int* __restrict__ dst,
                               const int* __restrict__ rowptr, int* __restrict__ cnt,
                               int* __restrict__ src_sorted, int E) {
    int e = blockIdx.x * blockDim.x + threadIdx.x;
    if (e < E) {
        int d = dst[e];
        int p = rowptr[d] + atomicAdd(&cnt[d], 1);
        src_sorted[p] = src[e];
    }
}

// ---------------- weight prep: Wt[c][k] = W[k][c] (fp16), fused q|k|v|s ----------------

__global__ __launch_bounds__(256) void prep_w_kernel(
    const float* __restrict__ Wq, const float* __restrict__ Wk,
    const float* __restrict__ Wv, const float* __restrict__ Ws,
    const float* __restrict__ bq, const float* __restrict__ bk,
    const float* __restrict__ bv, const float* __restrict__ bs,
    f16* __restrict__ Wt, float* __restrict__ bias, int K) {
    int idx = blockIdx.x * 256 + threadIdx.x;
    if (idx < 448) {
        bias[idx] = (idx < 128) ? bq[idx]
                  : (idx < 256) ? bk[idx - 128]
                  : (idx < 384) ? bv[idx - 256]
                  : bs[idx - 384];
    }
    if (idx >= 448 * K) return;
    int c = idx / K, k = idx - c * K;
    float v;
    if (c < 128)      v = Wq[k * 128 + c];
    else if (c < 256) v = Wk[k * 128 + (c - 128)];
    else if (c < 384) v = Wv[k * 128 + (c - 256)];
    else              v = Ws[k * 64 + (c - 384)];
    Wt[(size_t)c * K + k] = (f16)v;
}

// ---------------- fused MFMA GEMM: out[M][448] = X[M][K] @ W[K][448] + b ----------------
// Block: 256 threads / 4 waves; 64 rows x 448 cols per block. X tile staged once
// (converted from f32 for layer 1), A-fragments hoisted to registers, then loop
// over the 7 64-col W tiles in LDS. XOR-swizzle (byte ^= (row&7)<<4) on both tiles.

template <int K, bool F32IN>
__global__ __launch_bounds__(256) void gemm_qkvs_kernel(
    const void* __restrict__ Xv, const f16* __restrict__ Wt,
    const float* __restrict__ bias, f16* __restrict__ out, int M) {
    __shared__ f16 xa[64 * K];
    __shared__ f16 wb[64 * K];
    int row0 = blockIdx.x * 64;
    int tid = threadIdx.x;

    if (F32IN) {
        const float* X = (const float*)Xv;
        constexpr int CPR = K / 4;
        for (int c = tid; c < 64 * CPR; c += 256) {
            int r = c / CPR, kc = c % CPR;
            int gr = row0 + r;
            float4 v = {0.f, 0.f, 0.f, 0.f};
            if (gr < M) v = *(const float4*)(X + (size_t)gr * K + kc * 4);
            f16x4 hv = {(f16)v.x, (f16)v.y, (f16)v.z, (f16)v.w};
            int off = (r * K + kc * 4) * 2;
            off ^= (r & 7) << 4;
            *(f16x4*)((char*)xa + off) = hv;
        }
    } else {
        const f16* X = (const f16*)Xv;
        constexpr int CPR = K / 8;
        for (int c = tid; c < 64 * CPR; c += 256) {
            int r = c / CPR, kc = c % CPR;
            int gr = row0 + r;
            uint4 v = {0, 0, 0, 0};
            if (gr < M) v = *(const uint4*)(X + (size_t)gr * K + kc * 8);
            int off = (r * K + kc * 8) * 2;
            off ^= (r & 7) << 4;
            *(uint4*)((char*)xa + off) = v;
        }
    }
    __syncthreads();

    int lane = tid & 63, wid = tid >> 6;
    int fr = lane & 15, fk = lane >> 4;
    int arow = wid * 16 + fr;
    constexpr int NK = K / 32;
    f16x8 af[NK];
    #pragma unroll
    for (int ks = 0; ks < NK; ++ks) {
        int aoff = (arow * K + ks * 32 + fk * 8) * 2;
        aoff ^= (arow & 7) << 4;
        af[ks] = *(f16x8*)((char*)xa + aoff);
    }

    int orow = row0 + wid * 16 + fk * 4;
    constexpr int CPRW = K / 8;
    for (int ct = 0; ct < 7; ++ct) {
        if (ct > 0) __syncthreads();  // all waves done reading wb before overwrite
        int col0 = ct * 64;
        for (int c = tid; c < 64 * CPRW; c += 256) {
            int r = c / CPRW, kc = c % CPRW;
            uint4 v = *(const uint4*)(Wt + (size_t)(col0 + r) * K + kc * 8);
            int off = (r * K + kc * 8) * 2;
            off ^= (r & 7) << 4;
            *(uint4*)((char*)wb + off) = v;
        }
        __syncthreads();

        f32x4 acc[4] = {};
        #pragma unroll
        for (int ks = 0; ks < NK; ++ks) {
            #pragma unroll
            for (int cf = 0; cf < 4; ++cf) {
                int brow = cf * 16 + fr;
                int boff = (brow * K + ks * 32 + fk * 8) * 2;
                boff ^= (brow & 7) << 4;
                f16x8 bf = *(f16x8*)((char*)wb + boff);
                acc[cf] = __builtin_amdgcn_mfma_f32_16x16x32_f16(af[ks], bf, acc[cf], 0, 0, 0);
            }
        }

        int ocol = col0 + fr;
        #pragma unroll
        for (int cf = 0; cf < 4; ++cf) {
            float b = bias[ocol + cf * 16];
            #pragma unroll
            for (int r = 0; r < 4; ++r) {
                int gr = orow + r;
                if (gr < M) out[(size_t)gr * 448 + ocol + cf * 16] = (f16)(acc[cf][r] + b);
            }
        }
    }
}

// ---------------- fused per-node online-softmax attention ----------------
// One wave per node; lane = (e2:bits4-5, h:bit3, c8:bits0-2); 4 edges/iter,
// 8-channel f16x8 slice per lane. Deferred-max online softmax: common path is
// 3 dot-shfls + __any + 1 exp; rescale (2 shfls + exp + 8 mul) only when the
// running max grows by >6.

__global__ __launch_bounds__(256) void attn_kernel(
    const f16* __restrict__ T,  // [N][448] : q|k|v|s
    const int* __restrict__ rowptr, const int* __restrict__ srcs,
    f16* __restrict__ hout, float* __restrict__ fout, int n, int final_layer) {
    int node = blockIdx.x * 4 + (threadIdx.x >> 6);
    if (node >= n) return;
    int lane = threadIdx.x & 63;
    int c8 = lane & 7, e2 = lane >> 4;
    const size_t base = (size_t)node * 448;
    const int coff = ((lane >> 3) & 1) * 64 + c8 * 8;

    f16x8 q = *(const f16x8*)(T + base + coff);
    float m = -__builtin_inff(), s = 0.f;
    float av[8] = {};

    int beg = rowptr[node], end = rowptr[node + 1];
    for (int i0 = beg; i0 < end; i0 += 4) {
        int i = i0 + e2;
        bool valid = (i < end);
        int sidx = srcs[valid ? i : (end - 1)];
        const f16* p = T + (size_t)sidx * 448 + coff;
        f16x8 kv = *(const f16x8*)(p + 128);
        f16x8 vv = *(const f16x8*)(p + 256);
        float d = 0.f;
#ifdef HAVE_FDOT2
        #pragma unroll
        for (int j = 0; j < 4; ++j) {
            f16x2 qq = {q[2 * j], q[2 * j + 1]};
            f16x2 kk = {kv[2 * j], kv[2 * j + 1]};
            d = __builtin_amdgcn_fdot2(qq, kk, d, false);
        }
#else
        #pragma unroll
        for (int j = 0; j < 8; ++j) d += (float)q[j] * (float)kv[j];
#endif
        d += __shfl_xor(d, 1);
        d += __shfl_xor(d, 2);
        d += __shfl_xor(d, 4);
        d *= 0.125f;  // 1/sqrt(64)
        if (!valid) d = -__builtin_inff();

        if (__any(d > m + 6.f)) {
            float dmax = fmaxf(d, __shfl_xor(d, 16));
            dmax = fmaxf(dmax, __shfl_xor(dmax, 32));
            float nm = fmaxf(m, dmax);
            float f = __expf(m - nm);
            s *= f;
            #pragma unroll
            for (int j = 0; j < 8; ++j) av[j] *= f;
            m = nm;
        }
        float pe = __expf(d - m);
        s += pe;
        #pragma unroll
        for (int j = 0; j < 8; ++j) av[j] += pe * (float)vv[j];
    }

    // reduce partials over the 4 edge-groups (lane bits 4-5)
    s += __shfl_xor(s, 16);
    s += __shfl_xor(s, 32);
    float inv = 1.0f / (s + 1e-16f);
    float r[8];
    #pragma unroll
    for (int j = 0; j < 8; ++j) {
        float a = av[j];
        a += __shfl_xor(a, 16);
        a += __shfl_xor(a, 32);
        r[j] = a * inv;
    }
    // head mean: combine h=0 with h=1 (lane bit 3)
    #pragma unroll
    for (int j = 0; j < 8; ++j) r[j] = 0.5f * (r[j] + __shfl_xor(r[j], 8));

    if (lane < 8) {  // 8 lanes x 8 channels = 64 outputs
        f16x8 sk = *(const f16x8*)(T + base + 384 + c8 * 8);
        #pragma unroll
        for (int j = 0; j < 8; ++j) r[j] = fmaxf(r[j] + (float)sk[j], 0.f);
        if (final_layer) {
            float4* dst4 = (float4*)(fout + (size_t)node * 64 + c8 * 8);
            dst4[0] = make_float4(r[0], r[1], r[2], r[3]);
            dst4[1] = make_float4(r[4], r[5], r[6], r[7]);
        } else {
            f16x8 o = {(f16)r[0], (f16)r[1], (f16)r[2], (f16)r[3],
                       (f16)r[4], (f16)r[5], (f16)r[6], (f16)r[7]};
            *(f16x8*)(hout + (size_t)node * 64 + c8 * 8) = o;
        }
    }
}

// ---------------- launch ----------------

extern "C" void kernel_launch(void* const* d_in, const int* in_sizes, int n_in,
                              void* d_out, int out_size, void* d_ws, size_t ws_size,
                              hipStream_t stream) {
    const float* x = (const float*)d_in[0];
    const int* ei  = (const int*)d_in[1];
    const int N = in_sizes[0] / 128;
    const int E = in_sizes[1] / 2;
    const int* src = ei;
    const int* dst = ei + E;

    const float* Wq[3] = {(const float*)d_in[2],  (const float*)d_in[10], (const float*)d_in[18]};
    const float* bq[3] = {(const float*)d_in[3],  (const float*)d_in[11], (const float*)d_in[19]};
    const float* Wk[3] = {(const float*)d_in[4],  (const float*)d_in[12], (const float*)d_in[20]};
    const float* bk[3] = {(const float*)d_in[5],  (const float*)d_in[13], (const float*)d_in[21]};
    const float* Wv[3] = {(const float*)d_in[6],  (const float*)d_in[14], (const float*)d_in[22]};
    const float* bv[3] = {(const float*)d_in[7],  (const float*)d_in[15], (const float*)d_in[23]};
    const float* Wsk[3]= {(const float*)d_in[8],  (const float*)d_in[16], (const float*)d_in[24]};
    const float* bsk[3]= {(const float*)d_in[9],  (const float*)d_in[17], (const float*)d_in[25]};

    char* p = (char*)d_ws;
    int* rowptr   = (int*)p; p += (size_t)(N + 1) * 4;
    int* cnt      = (int*)p; p += (size_t)N * 4;
    int* srcs     = (int*)p; p += (size_t)E * 4;
    int* partials = (int*)p; p += 256 * 4;
    p = (char*)(((uintptr_t)p + 255) & ~(uintptr_t)255);
    f16* Xh   = (f16*)p; p += (size_t)N * 64 * 2;
    f16* QKVS = (f16*)p; p += (size_t)N * 448 * 2;
    f16* Wt   = (f16*)p; p += (size_t)448 * 128 * 2;
    float* bias = (float*)p; p += 448 * 4;
    if ((size_t)(p - (char*)d_ws) > ws_size) return;

    int nb = (N + 255) / 256;
    hipMemsetAsync(cnt, 0, (size_t)N * 4, stream);
    hist_kernel<<<(E + 255) / 256, 256, 0, stream>>>(dst, cnt, E);
    block_scan_kernel<<<nb, 256, 0, stream>>>(cnt, rowptr, partials, N);
    partial_scan_kernel<<<1, 256, 0, stream>>>(partials, nb);
    add_offsets_kernel<<<nb, 256, 0, stream>>>(rowptr, partials, N);
    hipMemsetAsync(cnt, 0, (size_t)N * 4, stream);
    scatter_kernel<<<(E + 255) / 256, 256, 0, stream>>>(src, dst, rowptr, cnt, srcs, E);

    int gx = (N + 63) / 64;
    for (int l = 0; l < 3; ++l) {
        int K = (l == 0) ? 128 : 64;
        prep_w_kernel<<<(448 * K + 255) / 256, 256, 0, stream>>>(
            Wq[l], Wk[l], Wv[l], Wsk[l], bq[l], bk[l], bv[l], bsk[l], Wt, bias, K);
        if (l == 0)
            gemm_qkvs_kernel<128, true><<<gx, 256, 0, stream>>>(x, Wt, bias, QKVS, N);
        else
            gemm_qkvs_kernel<64, false><<<gx, 256, 0, stream>>>(Xh, Wt, bias, QKVS, N);
        attn_kernel<<<(N + 3) / 4, 256, 0, stream>>>(
            QKVS, rowptr, srcs, Xh, (float*)d_out, N, (l == 2) ? 1 : 0);
    }
}